// Round 16
// baseline (770.522 us; speedup 1.0000x reference)
//
#include <hip/hip_runtime.h>
#include <hip/hip_bf16.h>
#include <cstdint>

// Problem constants (fixed by the reference)
#define NB 4
#define NH 128
#define NW 128
#define NC 256
#define NFF 1024
#define NE 4
#define NPATCH 4096   // B * 32 * 32
#define NPAIR 16      // ordered expert pairs (i1*4+i2), 12 valid
#define PPB 4         // patches per slot
#define BM 64         // token rows per slot (PPB*16)
#define FFC 128       // f-chunk width
#define NSLOT 1040    // max compact slots: sum ceil(n/4) <= 1024+12

typedef __attribute__((ext_vector_type(8))) short short8;
typedef __attribute__((ext_vector_type(8))) unsigned short ushort8;
typedef __attribute__((ext_vector_type(16))) float f32x16;

__device__ __forceinline__ unsigned short f2b(float f) {
  union { float f; uint32_t u; } v; v.f = f;
  uint32_t u = v.u + 0x7FFFu + ((v.u >> 16) & 1u);   // RNE
  return (unsigned short)(u >> 16);
}

__device__ __forceinline__ float gelu_f(float v) {
  float u = v * v;
  float t = __builtin_fmaf(u, 0.044715f, 1.0f) * v;
  float e = __builtin_amdgcn_exp2f(t * -2.3022083f);
  return v * __builtin_amdgcn_rcpf(1.0f + e);
}

__device__ __forceinline__ void bar_lgkm() {
  asm volatile("s_waitcnt lgkmcnt(0)" ::: "memory");
  __builtin_amdgcn_s_barrier();
}

// ---------------- weight fp32 -> bf16 (+ cnt zeroing) ----------------
__global__ __launch_bounds__(256) void convert_kernel(
    const float* __restrict__ W1, const float* __restrict__ W2,
    unsigned short* __restrict__ W1b, unsigned short* __restrict__ W2b,
    int* __restrict__ cnt, int n) {
  int i = blockIdx.x * blockDim.x + threadIdx.x;
  if (i < NPAIR) cnt[i] = 0;
  if (i < n) {
    W1b[i] = f2b(W1[i]);
    W2b[i] = f2b(W2[i]);
  }
}

// ---------------- router ----------------
__global__ __launch_bounds__(256) void router_kernel(
    const float* __restrict__ x, const float* __restrict__ Wg,
    int* __restrict__ cnt, int* __restrict__ plist, float2* __restrict__ wlist) {
  int p = blockIdx.x;
  int b = p >> 10, pi = p & 1023;
  int phi = pi >> 5, pwi = pi & 31;
  int c = threadIdx.x;

  const float* base = x + (((size_t)(b * NH + phi * 4) * NW) + pwi * 4) * NC + c;
  float s = 0.f;
#pragma unroll
  for (int i = 0; i < 4; i++)
#pragma unroll
    for (int j = 0; j < 4; j++)
      s += base[(i * NW + j) * NC];
  float mean = s * (1.f / 16.f);

  __shared__ float m_lds[NC];
  __shared__ double logit_lds[NE];
  m_lds[c] = mean;
  __syncthreads();

  int wid = c >> 6, lane = c & 63;
  {
    const float* wg = Wg + wid * NC;
    double acc = 0.0;
#pragma unroll
    for (int q = 0; q < 4; q++)
      acc += (double)m_lds[lane + q * 64] * (double)wg[lane + q * 64];
    for (int off = 32; off; off >>= 1) acc += __shfl_down(acc, off);
    if (lane == 0) logit_lds[wid] = acc;
  }
  __syncthreads();

  if (c == 0) {
    double l[NE], pp[NE];
    double mx = -1e300;
#pragma unroll
    for (int i = 0; i < NE; i++) { l[i] = logit_lds[i]; mx = fmax(mx, l[i]); }
    double sum = 0.0;
#pragma unroll
    for (int i = 0; i < NE; i++) { pp[i] = exp(l[i] - mx); sum += pp[i]; }
#pragma unroll
    for (int i = 0; i < NE; i++) pp[i] /= sum;
    int i1 = 0; double p1 = pp[0];
    for (int i = 1; i < NE; i++) if (pp[i] > p1) { p1 = pp[i]; i1 = i; }
    int i2 = -1; double p2 = -1.0;
    for (int i = 0; i < NE; i++) {
      if (i == i1) continue;
      if (pp[i] > p2) { p2 = pp[i]; i2 = i; }
    }
    double den = p1 + p2 + 1e-9;
    float w1 = (float)(p1 / den), w2 = (float)(p2 / den);
    int pr = i1 * NE + i2;
    int pos = atomicAdd(&cnt[pr], 1);
    plist[pr * NPATCH + pos] = p;
    wlist[pr * NPATCH + pos] = make_float2(w1, w2);
  }
}

// ---------------- worklist: compact slots ----------------
__global__ __launch_bounds__(64) void worklist_kernel(
    const int* __restrict__ cnt, int* __restrict__ wl) {
  int lane = threadIdx.x;
  if (lane < NPAIR) {
    int base = 0, mynb = 0;
    for (int q = 0; q < NPAIR; ++q) {
      int nb = (cnt[q] + PPB - 1) / PPB;
      if (q < lane) base += nb;
      if (q == lane) mynb = nb;
    }
    for (int i = 0; i < mynb; ++i)
      wl[1 + base + i] = (lane << 12) | (i * PPB);
    if (lane == NPAIR - 1) wl[0] = base + mynb;
  }
}

// H layout per (slot, local chunk c): 16 KiB of A-fragment pages:
// page (tt*8 + kkf) * 1024B + half*512 + t32*16 + (f&4)*2, where a reader
// lane l gets t=l&31, f = kkf*16 + (l>>5)*8 + j, read lane-linear at l*16B.

// ---------------- G1: H = gelu(X @ W1^T + b1) * w, barrier-free core ----------------
// 256 thr / 4 waves, 32 KiB LDS. After the X-gather barrier each wave is
// fully independent: wave handles expert-chunks c = wid, wid+4, ... of this
// group; per chunk, 4 f-strips of 32: 16x {W1 b128 (L2) + 2 Xf LDS reads +
// 2 MFMA} -> GELU + router-scale -> coalesced fragment-page stores to HBM.
// No inner barriers => compiler pipelines W1 loads across the whole chunk.
__global__ __launch_bounds__(256, 3) void g1_kernel(
    const float* __restrict__ x, const float* __restrict__ b1,
    const unsigned short* __restrict__ W1b, const int* __restrict__ cnt,
    const int* __restrict__ plist, const float2* __restrict__ wlist,
    const int* __restrict__ wl, unsigned short* __restrict__ Hbuf,
    int group, int cpg) {
  __shared__ unsigned short Xf[2 * 16 * 512];   // 32 KiB frag pages

  int s = blockIdx.x;
  if (s >= wl[0]) return;
  int ent = wl[1 + s];
  int pr = ent >> 12, pbase = ent & 4095;
  int e1 = pr >> 2, e2 = pr & 3;
  int n = cnt[pr];

  int tid = threadIdx.x, lane = tid & 63, wid = tid >> 6;
  int l31 = lane & 31, lh = lane >> 5;

  const int*    pl  = plist + pr * NPATCH + pbase;
  const float2* wlp = wlist + pr * NPATCH + pbase;

  float wvA[PPB], wvB[PPB];
#pragma unroll
  for (int q = 0; q < PPB; q++) {
    if (pbase + q < n) { float2 w = wlp[q]; wvA[q] = w.x; wvB[q] = w.y; }
    else { wvA[q] = 0.f; wvB[q] = 0.f; }
  }

  // ---- gather tokens -> Xf fragment pages ----
  {
    int r  = tid >> 2;            // 0..63 token row
    int c0 = (tid & 3) * 64;      // 64 channels per thread
    int pid = (pbase + (r >> 4) < n) ? pl[r >> 4] : -1;
    int t = r & 15;
    int tt = r >> 5, t32 = r & 31;
    if (pid >= 0) {
      int b = pid >> 10, pi = pid & 1023;
      int phi = pi >> 5, pwi = pi & 31;
      const float* src =
          x + (((size_t)(b * NH + phi * 4 + (t >> 2)) * NW) + pwi * 4 + (t & 3)) * NC + c0;
#pragma unroll
      for (int kb = 0; kb < 8; kb++) {
        float4 v0 = *reinterpret_cast<const float4*>(src + kb * 8);
        float4 v1 = *reinterpret_cast<const float4*>(src + kb * 8 + 4);
        ushort8 h;
        h[0] = f2b(v0.x); h[1] = f2b(v0.y); h[2] = f2b(v0.z); h[3] = f2b(v0.w);
        h[4] = f2b(v1.x); h[5] = f2b(v1.y); h[6] = f2b(v1.z); h[7] = f2b(v1.w);
        int k = c0 + kb * 8;
        int uidx = (tt * 16 + (k >> 4)) * 512 + (((k >> 3) & 1) * 32 + t32) * 8;
        *reinterpret_cast<ushort8*>(&Xf[uidx]) = h;
      }
    } else {
      ushort8 h = (ushort8)0;
#pragma unroll
      for (int kb = 0; kb < 8; kb++) {
        int k = c0 + kb * 8;
        int uidx = (tt * 16 + (k >> 4)) * 512 + (((k >> 3) & 1) * 32 + t32) * 8;
        *reinterpret_cast<ushort8*>(&Xf[uidx]) = h;
      }
    }
  }
  bar_lgkm();   // only barrier in the kernel

  for (int c = wid; c < cpg; c += 4) {
    int gc = group * cpg + c;
    int side = gc >> 3;            // 0: expert e1, 1: expert e2
    int fc = gc & 7;
    const unsigned short* W1e = W1b + (size_t)(side ? e2 : e1) * NFF * NC;
    const float* b1e = b1 + (side ? e2 : e1) * NFF;
    char* Hc = (char*)Hbuf + ((size_t)s * cpg + c) * 16384;

    for (int fs = 0; fs < 4; ++fs) {
      f32x16 a0 = (f32x16)0.f, a1 = (f32x16)0.f;
      const unsigned short* wrow =
          W1e + (size_t)(fc * FFC + fs * 32 + l31) * NC + lh * 8;
#pragma unroll
      for (int kf = 0; kf < 16; ++kf) {
        short8 aW = *reinterpret_cast<const short8*>(wrow + kf * 16);
        short8 bX0 = *reinterpret_cast<const short8*>(&Xf[(0 * 16 + kf) * 512 + lane * 8]);
        short8 bX1 = *reinterpret_cast<const short8*>(&Xf[(1 * 16 + kf) * 512 + lane * 8]);
        a0 = __builtin_amdgcn_mfma_f32_32x32x16_bf16(aW, bX0, a0, 0, 0, 0);
        a1 = __builtin_amdgcn_mfma_f32_32x32x16_bf16(aW, bX1, a1, 0, 0, 0);
      }

      // GELU + router-scale -> H (D[f][t]: t=l31, patch by l31>>4)
#pragma unroll
      for (int tt = 0; tt < 2; ++tt) {
        const f32x16& A = (tt == 0) ? a0 : a1;
        float wlo = side ? wvB[tt * 2]     : wvA[tt * 2];
        float whi = side ? wvB[tt * 2 + 1] : wvA[tt * 2 + 1];
        float w = (l31 >= 16) ? whi : wlo;
#pragma unroll
        for (int q = 0; q < 4; ++q) {
          int qs = q * 8 + lh * 4;   // f-local within this 32-f strip
          float4 bv = *reinterpret_cast<const float4*>(b1e + fc * FFC + fs * 32 + qs);
          ushort4 hp;
          hp.x = f2b(gelu_f(A[q * 4 + 0] + bv.x) * w);
          hp.y = f2b(gelu_f(A[q * 4 + 1] + bv.y) * w);
          hp.z = f2b(gelu_f(A[q * 4 + 2] + bv.z) * w);
          hp.w = f2b(gelu_f(A[q * 4 + 3] + bv.w) * w);
          int page = tt * 8 + fs * 2 + (qs >> 4);
          *reinterpret_cast<ushort4*>(
              Hc + page * 1024 + ((qs >> 3) & 1) * 512 + l31 * 16 + (qs & 4) * 2) = hp;
        }
      }
    }
  }
}

// ---------------- G2: Y += H @ W2^T — zero LDS, zero barriers ----------------
// 256 thr / 4 waves, no LDS. Wave = c-strip 64. H A-frags read lane-linear
// straight from global (16 KiB/chunk/slot; 4 waves share it through L1/L2).
// acc (4x f32x16) persists over the launch's cpg chunks; groups > 0
// accumulate into out via non-racing read-modify-write (each output element
// is owned by exactly one slot/wave/lane).
__global__ __launch_bounds__(256, 3) void g2_kernel(
    const float* __restrict__ b2, const unsigned short* __restrict__ W2b,
    const int* __restrict__ cnt, const int* __restrict__ plist,
    const float2* __restrict__ wlist, const int* __restrict__ wl,
    const unsigned short* __restrict__ Hbuf, float* __restrict__ out,
    int group, int cpg) {
  int s = blockIdx.x;
  if (s >= wl[0]) return;
  int ent = wl[1 + s];
  int pr = ent >> 12, pbase = ent & 4095;
  int e1 = pr >> 2, e2 = pr & 3;
  int n = cnt[pr];

  int tid = threadIdx.x, lane = tid & 63, wid = tid >> 6;
  int l31 = lane & 31, lh = lane >> 5;

  const int*    pl  = plist + pr * NPATCH + pbase;
  const float2* wlp = wlist + pr * NPATCH + pbase;

  float wvA[PPB], wvB[PPB];
#pragma unroll
  for (int q = 0; q < PPB; q++) {
    if (pbase + q < n) { float2 w = wlp[q]; wvA[q] = w.x; wvB[q] = w.y; }
    else { wvA[q] = 0.f; wvB[q] = 0.f; }
  }

  int wc = wid;
  f32x16 y00 = (f32x16)0.f, y01 = (f32x16)0.f;
  f32x16 y10 = (f32x16)0.f, y11 = (f32x16)0.f;

  for (int c = 0; c < cpg; ++c) {
    int gc = group * cpg + c;
    int side = gc >> 3;
    int fc = gc & 7;
    const unsigned short* W2e = W2b + (size_t)(side ? e2 : e1) * NC * NFF;
    const char* Hc = (const char*)Hbuf + ((size_t)s * cpg + c) * 16384;
    const unsigned short* w0 = W2e + (size_t)(wc * 64 + l31) * NFF + fc * FFC + lh * 8;
    const unsigned short* w1 = W2e + (size_t)(wc * 64 + 32 + l31) * NFF + fc * FFC + lh * 8;
#pragma unroll
    for (int kkf = 0; kkf < 8; ++kkf) {
      short8 aH0 = *reinterpret_cast<const short8*>(Hc + kkf * 1024 + lane * 16);
      short8 aH1 = *reinterpret_cast<const short8*>(Hc + 8192 + kkf * 1024 + lane * 16);
      short8 bW0 = *reinterpret_cast<const short8*>(w0 + kkf * 16);
      short8 bW1 = *reinterpret_cast<const short8*>(w1 + kkf * 16);
      y00 = __builtin_amdgcn_mfma_f32_32x32x16_bf16(aH0, bW0, y00, 0, 0, 0);
      y01 = __builtin_amdgcn_mfma_f32_32x32x16_bf16(aH1, bW0, y01, 0, 0, 0);
      y10 = __builtin_amdgcn_mfma_f32_32x32x16_bf16(aH0, bW1, y10, 0, 0, 0);
      y11 = __builtin_amdgcn_mfma_f32_32x32x16_bf16(aH1, bW1, y11, 0, 0, 0);
    }
  }

  // ---- epilogue: group 0 stores Y + bias; groups > 0 accumulate ----
#pragma unroll
  for (int ct = 0; ct < 2; ++ct) {
    int cc = wc * 64 + ct * 32 + l31;
    float bA = b2[e1 * NC + cc];
    float bB = b2[e2 * NC + cc];
#pragma unroll
    for (int tt = 0; tt < 2; ++tt) {
      const f32x16& Y = (ct == 0) ? ((tt == 0) ? y00 : y01)
                                  : ((tt == 0) ? y10 : y11);
#pragma unroll
      for (int q = 0; q < 4; ++q) {
        int pslot = tt * 2 + (q >> 1);
        if (pbase + pslot >= n) continue;
        int pid = pl[pslot];
        float wA = wvA[pslot], wB = wvB[pslot];
        int b = pid >> 10, pi = pid & 1023;
        int phi = pi >> 5, pwi = pi & 31;
        float bias = wA * bA + wB * bB;
#pragma unroll
        for (int i = 0; i < 4; ++i) {
          int tok = 8 * (q & 1) + 4 * lh + i;
          float* dst =
              out + (((size_t)(b * NH + phi * 4 + (tok >> 2)) * NW) + pwi * 4 + (tok & 3)) * NC;
          if (group == 0) dst[cc] = Y[q * 4 + i] + bias;
          else            dst[cc] = dst[cc] + Y[q * 4 + i];
        }
      }
    }
  }
}

extern "C" void kernel_launch(void* const* d_in, const int* in_sizes, int n_in,
                              void* d_out, int out_size, void* d_ws, size_t ws_size,
                              hipStream_t stream) {
  const float* x  = (const float*)d_in[0];
  const float* Wg = (const float*)d_in[1];
  const float* W1 = (const float*)d_in[2];
  const float* b1 = (const float*)d_in[3];
  const float* W2 = (const float*)d_in[4];
  const float* b2 = (const float*)d_in[5];
  float* out = (float*)d_out;

  char* ws = (char*)d_ws;
  unsigned short* W1b = (unsigned short*)ws;                                  // 2 MiB
  unsigned short* W2b = (unsigned short*)(ws + (size_t)2 * 1024 * 1024);      // 2 MiB
  int*    cnt   = (int*)(ws + (size_t)4 * 1024 * 1024);                       // 64 B
  int*    plist = (int*)(ws + (size_t)4 * 1024 * 1024 + 256);                 // 256 KiB
  float2* wlist = (float2*)(ws + (size_t)4 * 1024 * 1024 + 256 +
                            (size_t)NPAIR * NPATCH * sizeof(int));            // 512 KiB
  int*    wl    = (int*)(ws + (size_t)5 * 1024 * 1024);                       // ~4.2 KiB

  size_t hoff = (size_t)5 * 1024 * 1024 + 65536;
  unsigned short* Hbuf = (unsigned short*)(ws + hoff);

  // dynamic f-group count by available workspace (H slice = NSLOT*cpg*16KiB)
  int ngroups, cpg;
  if (ws_size >= hoff + (size_t)NSLOT * 16 * 16384)      { ngroups = 1; cpg = 16; }
  else if (ws_size >= hoff + (size_t)NSLOT * 8 * 16384)  { ngroups = 2; cpg = 8;  }
  else                                                   { ngroups = 4; cpg = 4;  }

  convert_kernel<<<dim3(4096), dim3(256), 0, stream>>>(W1, W2, W1b, W2b, cnt, NE * NFF * NC);
  router_kernel<<<dim3(NPATCH), dim3(256), 0, stream>>>(x, Wg, cnt, plist, wlist);
  worklist_kernel<<<dim3(1), dim3(64), 0, stream>>>(cnt, wl);

  for (int g = 0; g < ngroups; ++g) {
    g1_kernel<<<dim3(NSLOT), dim3(256), 0, stream>>>(
        x, b1, W1b, cnt, plist, wlist, wl, Hbuf, g, cpg);
    g2_kernel<<<dim3(NSLOT), dim3(256), 0, stream>>>(
        b2, W2b, cnt, plist, wlist, wl, Hbuf, out, g, cpg);
  }
}